// Round 4
// baseline (747.746 us; speedup 1.0000x reference)
//
#include <hip/hip_runtime.h>
#include <hip/hip_bf16.h>
#include <math.h>

typedef __hip_bfloat16 bf16;
typedef short bf16x8 __attribute__((ext_vector_type(8)));
typedef float f32x4 __attribute__((ext_vector_type(4)));

#define EPSV 1e-5f

__device__ __forceinline__ float gelu_exact(float x) {
    return 0.5f * x * (1.0f + erff(x * 0.70710678118654752f));
}

__device__ __forceinline__ void block_reduce2(float& a, float& b, float* sm) {
    #pragma unroll
    for (int off = 32; off > 0; off >>= 1) {
        a += __shfl_down(a, off);
        b += __shfl_down(b, off);
    }
    int lane = threadIdx.x & 63, wid = threadIdx.x >> 6;
    int nw = blockDim.x >> 6;
    if (lane == 0) { sm[wid*2] = a; sm[wid*2+1] = b; }
    __syncthreads();
    if (threadIdx.x == 0) {
        for (int i = 1; i < nw; ++i) { a += sm[i*2]; b += sm[i*2+1]; }
    }
}

__device__ __forceinline__ unsigned pk_bf2(float lo, float hi) {
    union { __hip_bfloat162 b2; unsigned u; } cv;
    cv.b2 = __float22bfloat162_rn(make_float2(lo, hi));
    return cv.u;
}

__device__ __forceinline__ void gload_lds16(const void* g, void* l) {
    __builtin_amdgcn_global_load_lds(
        (const __attribute__((address_space(1))) void*)g,
        (__attribute__((address_space(3))) void*)l, 16, 0, 0);
}

// ---------------- KW+K0 merged: w2 transpose (blocks 0..5183) + GN0 stats (5184..6207) ----
__global__ __launch_bounds__(256) void kw_k0(
    const float* __restrict__ w2, bf16* __restrict__ wt2,
    const float* __restrict__ x, float* __restrict__ stats)
{
    __shared__ float sm[16];
    int b = blockIdx.x;
    if (b < 5184) {
        int idx = b * 256 + threadIdx.x;   // exactly 81*128*128
        int tap = idx >> 14;
        int r = idx & 16383;
        int o = r >> 7;
        int ci = r & 127;
        wt2[idx] = __float2bfloat16(w2[(o * 128 + ci) * 81 + tap]);
    } else {
        const float4* x4 = (const float4*)x;
        int idx = (b - 5184) * 256 + threadIdx.x;
        float s = 0.f, q = 0.f;
        for (int i = idx; i < (1 << 19); i += 1024 * 256) {
            float4 v = x4[i];
            s += v.x + v.y + v.z + v.w;
            q += v.x*v.x + v.y*v.y + v.z*v.z + v.w*v.w;
        }
        block_reduce2(s, q, sm);
        if (threadIdx.x == 0) { atomicAdd(&stats[0], s); atomicAdd(&stats[1], q); }
    }
}

// ---------------- K1: GN0-apply folded into conv1 (32->128), + GN1 stats ----------------
__global__ __launch_bounds__(256) void k1_conv1(
    const float* __restrict__ x, const float* __restrict__ w1,
    const float* __restrict__ g0w, const float* __restrict__ g0b,
    float* __restrict__ h1, float* __restrict__ stats)
{
    __shared__ float We[128 * 32];
    __shared__ float Be[128];
    __shared__ float sm[16];
    float mu = stats[0] * (1.f / 2097152.f);
    float var = stats[1] * (1.f / 2097152.f) - mu * mu;
    float rs = rsqrtf(var + EPSV);
    int t = threadIdx.x;
    for (int i = t; i < 128 * 32; i += 256) {
        int ci = i & 31;
        We[i] = w1[i] * g0w[ci] * rs;
    }
    if (t < 128) {
        float acc = 0.f;
        for (int ci = 0; ci < 32; ++ci)
            acc += w1[t * 32 + ci] * (g0b[ci] - mu * rs * g0w[ci]);
        Be[t] = acc;
    }
    __syncthreads();
    int s = blockIdx.x * 256 + t;
    float xv[32];
    #pragma unroll
    for (int ci = 0; ci < 32; ++ci) xv[ci] = x[ci * 65536 + s];
    float lsum = 0.f, lsq = 0.f;
    for (int o = 0; o < 128; ++o) {
        float acc = Be[o];
        const float4* wr = (const float4*)&We[o * 32];
        #pragma unroll
        for (int c4 = 0; c4 < 8; ++c4) {
            float4 w = wr[c4];
            acc += w.x * xv[c4*4] + w.y * xv[c4*4+1] + w.z * xv[c4*4+2] + w.w * xv[c4*4+3];
        }
        h1[o * 65536 + s] = acc;
        lsum += acc; lsq += acc * acc;
    }
    block_reduce2(lsum, lsq, sm);
    if (t == 0) { atomicAdd(&stats[2], lsum); atomicAdd(&stats[3], lsq); }
}

// ---------------- K2: GN1 apply + GELU -> padded bf16 P[18^4][128] ----------------
__global__ __launch_bounds__(256) void k2_gn1_pad(
    const float* __restrict__ h1, bf16* __restrict__ P, const float* __restrict__ stats,
    const float* __restrict__ gw, const float* __restrict__ gb)
{
    __shared__ float tile[128 * 65];
    float mu = stats[2] * (1.f / 8388608.f);
    float var = stats[3] * (1.f / 8388608.f) - mu * mu;
    float rs = rsqrtf(var + EPSV);
    int t = threadIdx.x;
    int sbase = blockIdx.x * 64;
    for (int p = 0; p < 32; ++p) {
        int idx = p * 256 + t;
        int ci = idx >> 6, sl = idx & 63;
        float v = h1[ci * 65536 + sbase + sl];
        v = (v - mu) * rs * gw[ci] + gb[ci];
        tile[ci * 65 + sl] = gelu_exact(v);
    }
    __syncthreads();
    for (int p = 0; p < 4; ++p) {
        int idx = p * 256 + t;          // 1024 units: 64 rows x 16 ci-groups
        int r = idx >> 4, cg = idx & 15;
        int s = sbase + r;
        int w = s & 15, z = (s >> 4) & 15, y = (s >> 8) & 15, xx = s >> 12;
        int prow = (((xx + 1) * 18 + y + 1) * 18 + z + 1) * 18 + w + 1;
        int c0 = cg * 8;
        uint4 u;
        u.x = pk_bf2(tile[(c0+0)*65 + r], tile[(c0+1)*65 + r]);
        u.y = pk_bf2(tile[(c0+2)*65 + r], tile[(c0+3)*65 + r]);
        u.z = pk_bf2(tile[(c0+4)*65 + r], tile[(c0+5)*65 + r]);
        u.w = pk_bf2(tile[(c0+6)*65 + r], tile[(c0+7)*65 + r]);
        *(uint4*)((char*)P + ((size_t)prow * 256 + c0 * 2)) = u;
    }
}

// ---------------- K3: 3^4 conv 128->128 via MFMA bf16, + GN2 stats ----------------
// Grid 512 = (X 16, Y 16, Zhalf 2), XCD-chunk swizzled. 256 thr = 4 waves;
// wave tile 64 spatial x 64 o. A staged in LDS (XOR-swizzled); B read DIRECT
// from global (L1/L2-hot, 32KB per tap) -> no Ws LDS, no per-tap barrier.
__global__ __launch_bounds__(256, 3) void k3_conv2(
    const bf16* __restrict__ P, const bf16* __restrict__ wt2,
    float* __restrict__ h2, float* __restrict__ stats)
{
    __shared__ __align__(16) short As[23040];   // 180 rows x 128 ci, XOR-swizzled (45KB)
    __shared__ float sm[16];
    int t = threadIdx.x;
    int lane = t & 63, ww = t >> 6;
    int lo = lane & 15, hi = lane >> 4;
    // XCD-chunked bijective swizzle: HW bid i -> XCD i%8 owns logical chunk of 64
    int b = ((blockIdx.x & 7) << 6) | (blockIdx.x >> 3);
    int X = b >> 5, Y = (b >> 1) & 15, Z0 = (b & 1) * 8;
    int zg = ww >> 1, og = ww & 1;

    const char* Pb = (const char*)P;
    const char* Wb = (const char*)wt2;

    // B fragment global base per n (row = o, within-row k offset hi*16B), tap-invariant
    const char* wbase[4];
    #pragma unroll
    for (int n = 0; n < 4; ++n)
        wbase[n] = Wb + (og * 64 + n * 16 + lo) * 256 + hi * 16;

    f32x4 acc[4][4];
    #pragma unroll
    for (int m = 0; m < 4; ++m)
        #pragma unroll
        for (int n = 0; n < 4; ++n) acc[m][n] = (f32x4){0.f, 0.f, 0.f, 0.f};

    for (int kxy = 0; kxy < 9; ++kxy) {
        int kx = kxy / 3, ky = kxy - kx * 3;
        __syncthreads();   // prior readers of As done
        // stage 180 contiguous P rows: (X+kx, Y+ky, z'=Z0..Z0+9, w'=0..17) x 128ci bf16
        int rowstart = ((X + kx) * 18 + (Y + ky)) * 324 + Z0 * 18;
        const char* gA = Pb + (size_t)rowstart * 256;
        for (int c = ww; c < 45; c += 4) {
            int L = c * 1024 + lane * 16;
            int srcoff = L ^ (((L >> 8) & 7) << 4);   // pre-swizzle source (rule #21)
            gload_lds16(gA + srcoff, (char*)As + c * 1024);
        }
        __syncthreads();   // As ready (barrier drains vmcnt)
        #pragma unroll
        for (int t9 = 0; t9 < 9; ++t9) {
            int kz = t9 / 3, kw = t9 - kz * 3;
            int tap = kxy * 9 + t9;
            size_t toff = (size_t)tap * 32768;
            int abase[4], axor[4];
            #pragma unroll
            for (int m = 0; m < 4; ++m) {
                int row = (zg * 4 + m + kz) * 18 + lo + kw;
                abase[m] = row << 8;
                axor[m] = (row & 7) << 4;
            }
            #pragma unroll
            for (int kk = 0; kk < 4; ++kk) {
                int cb = kk * 64 + hi * 16;
                bf16x8 a[4], bb[4];
                #pragma unroll
                for (int m = 0; m < 4; ++m)
                    a[m] = *(const bf16x8*)((const char*)As + abase[m] + (cb ^ axor[m]));
                #pragma unroll
                for (int n = 0; n < 4; ++n)
                    bb[n] = *(const bf16x8*)(wbase[n] + toff + kk * 64);
                #pragma unroll
                for (int m = 0; m < 4; ++m)
                    #pragma unroll
                    for (int n = 0; n < 4; ++n)
                        acc[m][n] = __builtin_amdgcn_mfma_f32_16x16x32_bf16(
                            a[m], bb[n], acc[m][n], 0, 0, 0);
            }
        }
    }

    // epilogue: D frag col(lane&15)=o, row((lane>>4)*4+e)=w  -> float4 store along w
    float ls = 0.f, lq = 0.f;
    int sXY = (X * 16 + Y) * 16;
    #pragma unroll
    for (int m = 0; m < 4; ++m) {
        int z = Z0 + zg * 4 + m;
        int s = (sXY + z) * 16 + hi * 4;
        #pragma unroll
        for (int n = 0; n < 4; ++n) {
            int o = og * 64 + n * 16 + lo;
            *(f32x4*)(h2 + (size_t)o * 65536 + s) = acc[m][n];
            #pragma unroll
            for (int e = 0; e < 4; ++e) { float v = acc[m][n][e]; ls += v; lq += v * v; }
        }
    }
    __syncthreads();
    block_reduce2(ls, lq, sm);
    if (t == 0) { atomicAdd(&stats[4], ls); atomicAdd(&stats[5], lq); }
}

// ---------------- K4: GN2 apply + GELU in place + per-channel sums for SE ----------------
__global__ __launch_bounds__(256) void k4_gn2_se(
    float* __restrict__ h2, const float* __restrict__ stats,
    const float* __restrict__ gw, const float* __restrict__ gb,
    float* __restrict__ chansum)
{
    __shared__ float sm[4];
    float mu = stats[4] * (1.f / 8388608.f);
    float var = stats[5] * (1.f / 8388608.f) - mu * mu;
    float rs = rsqrtf(var + EPSV);
    int chan = blockIdx.x >> 4, seg = blockIdx.x & 15;
    float w = gw[chan], bb = gb[chan];
    float lsum = 0.f;
    int base = chan * 65536 + seg * 4096;
    for (int k = 0; k < 16; ++k) {
        int i = base + k * 256 + threadIdx.x;
        float v = gelu_exact((h2[i] - mu) * rs * w + bb);
        h2[i] = v;
        lsum += v;
    }
    #pragma unroll
    for (int off = 32; off > 0; off >>= 1) lsum += __shfl_down(lsum, off);
    int lane = threadIdx.x & 63, wid = threadIdx.x >> 6;
    if (lane == 0) sm[wid] = lsum;
    __syncthreads();
    if (threadIdx.x == 0) atomicAdd(&chansum[chan], sm[0] + sm[1] + sm[2] + sm[3]);
}

// ---------------- K6: SE MLP inline + conv3 (128->32) + GN3 stats ----------------
__global__ __launch_bounds__(256) void k6_conv3(
    const float* __restrict__ h2, const float* __restrict__ w3,
    const float* __restrict__ chansum,
    const float* __restrict__ sw1, const float* __restrict__ sw2,
    float* __restrict__ h3, float* __restrict__ stats)
{
    __shared__ float We[128 * 32];   // [ci][oc]
    __shared__ float sesc[128];
    __shared__ float t1s[8];
    __shared__ float sm[16];
    int t = threadIdx.x;
    // inline SE MLP (redundant per block, ~2K MAC)
    if (t < 8) {
        float a = 0.f;
        for (int o = 0; o < 128; ++o) a += sw1[t * 128 + o] * chansum[o];
        t1s[t] = gelu_exact(a * (1.f / 65536.f));
    }
    __syncthreads();
    if (t < 128) {
        float a = 0.f;
        #pragma unroll
        for (int d = 0; d < 8; ++d) a += sw2[t * 8 + d] * t1s[d];
        sesc[t] = 1.f / (1.f + expf(-a));
    }
    __syncthreads();
    for (int i = t; i < 4096; i += 256) {
        int ci = i >> 5, oc = i & 31;
        We[i] = w3[oc * 128 + ci] * sesc[ci];
    }
    __syncthreads();
    int s = blockIdx.x * 256 + t;
    float acc[32];
    #pragma unroll
    for (int j = 0; j < 32; ++j) acc[j] = 0.f;
    for (int ci = 0; ci < 128; ++ci) {
        float hv = h2[ci * 65536 + s];
        const float4* wr = (const float4*)&We[ci * 32];
        #pragma unroll
        for (int j4 = 0; j4 < 8; ++j4) {
            float4 wv = wr[j4];
            acc[j4*4+0] += hv * wv.x; acc[j4*4+1] += hv * wv.y;
            acc[j4*4+2] += hv * wv.z; acc[j4*4+3] += hv * wv.w;
        }
    }
    float ls = 0.f, lq = 0.f;
    #pragma unroll
    for (int j = 0; j < 32; ++j) {
        float v = acc[j];
        h3[j * 65536 + s] = v;
        ls += v; lq += v * v;
    }
    block_reduce2(ls, lq, sm);
    if (t == 0) { atomicAdd(&stats[6], ls); atomicAdd(&stats[7], lq); }
}

// ---------------- K7: GN3 apply -> out ----------------
__global__ __launch_bounds__(256) void k7_gn3(
    const float* __restrict__ h3, const float* __restrict__ stats,
    const float* __restrict__ gw, const float* __restrict__ gb,
    float* __restrict__ out)
{
    float mu = stats[6] * (1.f / 2097152.f);
    float var = stats[7] * (1.f / 2097152.f) - mu * mu;
    float rs = rsqrtf(var + EPSV);
    int idx = blockIdx.x * 256 + threadIdx.x;
    int c = idx >> 16;
    out[idx] = (h3[idx] - mu) * rs * gw[c] + gb[c];
}

// ---------------- launch ----------------
extern "C" void kernel_launch(void* const* d_in, const int* in_sizes, int n_in,
                              void* d_out, int out_size, void* d_ws, size_t ws_size,
                              hipStream_t stream)
{
    const float* x    = (const float*)d_in[0];
    const float* g0w  = (const float*)d_in[1];
    const float* g0b  = (const float*)d_in[2];
    const float* w1   = (const float*)d_in[3];
    const float* gn1w = (const float*)d_in[4];
    const float* gn1b = (const float*)d_in[5];
    const float* w2   = (const float*)d_in[6];
    const float* gn2w = (const float*)d_in[7];
    const float* gn2b = (const float*)d_in[8];
    const float* sw1  = (const float*)d_in[9];
    const float* sw2  = (const float*)d_in[10];
    const float* w3   = (const float*)d_in[11];
    const float* gn3w = (const float*)d_in[12];
    const float* gn3b = (const float*)d_in[13];
    float* out = (float*)d_out;

    char* ws = (char*)d_ws;
    float* stats   = (float*)ws;            // [0..7] sums, [64..191] chansum
    float* chansum = stats + 64;
    bf16*  wt2  = (bf16*)(ws + 4096);                 // 81*128*128 bf16 = 2,654,208 B
    bf16*  P    = (bf16*)(ws + 2658304);              // 18^4 x 128 bf16 = 26,873,856 B
    float* hbuf = (float*)(ws + 29532160);            // h1 then h2, 33,554,432 B
    float* h3   = (float*)(ws + 63086592);            // 8,388,608 B

    hipMemsetAsync(stats, 0, 4096, stream);
    hipMemsetAsync(P, 0, (size_t)104976 * 128 * 2, stream);
    kw_k0<<<6208, 256, 0, stream>>>(w2, wt2, x, stats);
    k1_conv1<<<256, 256, 0, stream>>>(x, w1, g0w, g0b, hbuf, stats);
    k2_gn1_pad<<<1024, 256, 0, stream>>>(hbuf, P, stats, gn1w, gn1b);
    k3_conv2<<<512, 256, 0, stream>>>(P, wt2, hbuf, stats);
    k4_gn2_se<<<2048, 256, 0, stream>>>(hbuf, stats, gn2w, gn2b, chansum);
    k6_conv3<<<256, 256, 0, stream>>>(hbuf, w3, chansum, sw1, sw2, h3, stats);
    k7_gn3<<<8192, 256, 0, stream>>>(h3, stats, gn3w, gn3b, out);
}

// Round 6
// 394.027 us; speedup vs baseline: 1.8977x; 1.8977x over previous
//
#include <hip/hip_runtime.h>
#include <hip/hip_bf16.h>
#include <math.h>

typedef __hip_bfloat16 bf16;
typedef short bf16x8 __attribute__((ext_vector_type(8)));
typedef float f32x4 __attribute__((ext_vector_type(4)));

#define EPSV 1e-5f

__device__ __forceinline__ float gelu_exact(float x) {
    return 0.5f * x * (1.0f + erff(x * 0.70710678118654752f));
}

__device__ __forceinline__ void block_reduce2(float& a, float& b, float* sm) {
    #pragma unroll
    for (int off = 32; off > 0; off >>= 1) {
        a += __shfl_down(a, off);
        b += __shfl_down(b, off);
    }
    int lane = threadIdx.x & 63, wid = threadIdx.x >> 6;
    int nw = blockDim.x >> 6;
    if (lane == 0) { sm[wid*2] = a; sm[wid*2+1] = b; }
    __syncthreads();
    if (threadIdx.x == 0) {
        for (int i = 1; i < nw; ++i) { a += sm[i*2]; b += sm[i*2+1]; }
    }
}

__device__ __forceinline__ unsigned pk_bf2(float lo, float hi) {
    union { __hip_bfloat162 b2; unsigned u; } cv;
    cv.b2 = __float22bfloat162_rn(make_float2(lo, hi));
    return cv.u;
}

__device__ __forceinline__ void gload_lds16(const void* g, void* l) {
    __builtin_amdgcn_global_load_lds(
        (const __attribute__((address_space(1))) void*)g,
        (__attribute__((address_space(3))) void*)l, 16, 0, 0);
}

// ---------------- KW+K0 merged: w2 transpose (blocks 0..5183) + GN0 stats (5184..6207) ----
__global__ __launch_bounds__(256) void kw_k0(
    const float* __restrict__ w2, bf16* __restrict__ wt2,
    const float* __restrict__ x, float* __restrict__ stats)
{
    __shared__ float sm[16];
    int b = blockIdx.x;
    if (b < 5184) {
        int idx = b * 256 + threadIdx.x;   // exactly 81*128*128
        int tap = idx >> 14;
        int r = idx & 16383;
        int o = r >> 7;
        int ci = r & 127;
        wt2[idx] = __float2bfloat16(w2[(o * 128 + ci) * 81 + tap]);
    } else {
        const float4* x4 = (const float4*)x;
        int idx = (b - 5184) * 256 + threadIdx.x;
        float s = 0.f, q = 0.f;
        for (int i = idx; i < (1 << 19); i += 1024 * 256) {
            float4 v = x4[i];
            s += v.x + v.y + v.z + v.w;
            q += v.x*v.x + v.y*v.y + v.z*v.z + v.w*v.w;
        }
        block_reduce2(s, q, sm);
        if (threadIdx.x == 0) { atomicAdd(&stats[0], s); atomicAdd(&stats[1], q); }
    }
}

// ---------------- K1: GN0-apply folded into conv1 (32->128), + GN1 stats ----------------
__global__ __launch_bounds__(256) void k1_conv1(
    const float* __restrict__ x, const float* __restrict__ w1,
    const float* __restrict__ g0w, const float* __restrict__ g0b,
    float* __restrict__ h1, float* __restrict__ stats)
{
    __shared__ float We[128 * 32];
    __shared__ float Be[128];
    __shared__ float sm[16];
    float mu = stats[0] * (1.f / 2097152.f);
    float var = stats[1] * (1.f / 2097152.f) - mu * mu;
    float rs = rsqrtf(var + EPSV);
    int t = threadIdx.x;
    for (int i = t; i < 128 * 32; i += 256) {
        int ci = i & 31;
        We[i] = w1[i] * g0w[ci] * rs;
    }
    if (t < 128) {
        float acc = 0.f;
        for (int ci = 0; ci < 32; ++ci)
            acc += w1[t * 32 + ci] * (g0b[ci] - mu * rs * g0w[ci]);
        Be[t] = acc;
    }
    __syncthreads();
    int s = blockIdx.x * 256 + t;
    float xv[32];
    #pragma unroll
    for (int ci = 0; ci < 32; ++ci) xv[ci] = x[ci * 65536 + s];
    float lsum = 0.f, lsq = 0.f;
    for (int o = 0; o < 128; ++o) {
        float acc = Be[o];
        const float4* wr = (const float4*)&We[o * 32];
        #pragma unroll
        for (int c4 = 0; c4 < 8; ++c4) {
            float4 w = wr[c4];
            acc += w.x * xv[c4*4] + w.y * xv[c4*4+1] + w.z * xv[c4*4+2] + w.w * xv[c4*4+3];
        }
        h1[o * 65536 + s] = acc;
        lsum += acc; lsq += acc * acc;
    }
    block_reduce2(lsum, lsq, sm);
    if (t == 0) { atomicAdd(&stats[2], lsum); atomicAdd(&stats[3], lsq); }
}

// ---------------- K2: GN1 apply + GELU -> padded bf16 P[18^4][128] ----------------
__global__ __launch_bounds__(256) void k2_gn1_pad(
    const float* __restrict__ h1, bf16* __restrict__ P, const float* __restrict__ stats,
    const float* __restrict__ gw, const float* __restrict__ gb)
{
    __shared__ float tile[128 * 65];
    float mu = stats[2] * (1.f / 8388608.f);
    float var = stats[3] * (1.f / 8388608.f) - mu * mu;
    float rs = rsqrtf(var + EPSV);
    int t = threadIdx.x;
    int sbase = blockIdx.x * 64;
    for (int p = 0; p < 32; ++p) {
        int idx = p * 256 + t;
        int ci = idx >> 6, sl = idx & 63;
        float v = h1[ci * 65536 + sbase + sl];
        v = (v - mu) * rs * gw[ci] + gb[ci];
        tile[ci * 65 + sl] = gelu_exact(v);
    }
    __syncthreads();
    for (int p = 0; p < 4; ++p) {
        int idx = p * 256 + t;          // 1024 units: 64 rows x 16 ci-groups
        int r = idx >> 4, cg = idx & 15;
        int s = sbase + r;
        int w = s & 15, z = (s >> 4) & 15, y = (s >> 8) & 15, xx = s >> 12;
        int prow = (((xx + 1) * 18 + y + 1) * 18 + z + 1) * 18 + w + 1;
        int c0 = cg * 8;
        uint4 u;
        u.x = pk_bf2(tile[(c0+0)*65 + r], tile[(c0+1)*65 + r]);
        u.y = pk_bf2(tile[(c0+2)*65 + r], tile[(c0+3)*65 + r]);
        u.z = pk_bf2(tile[(c0+4)*65 + r], tile[(c0+5)*65 + r]);
        u.w = pk_bf2(tile[(c0+6)*65 + r], tile[(c0+7)*65 + r]);
        *(uint4*)((char*)P + ((size_t)prow * 256 + c0 * 2)) = u;
    }
}

// ---------------- K3: 3^4 conv 128->128 via MFMA bf16, + GN2 stats ----------------
// 256 blocks (X,Y), 512 thr = 8 waves; block = 256 spatial (16z x 16w) x 128 o.
// As = full 18x18 slab (83KB, one contiguous 324-row range). Ws double-buffered
// (2x32KB), counted vmcnt(4) + raw barriers (no full drain in steady state).
// Taps consumed kw-major so 24 A-frags (regs) serve 3 kz taps each.
__global__ __launch_bounds__(512, 2) void k3_conv2(
    const bf16* __restrict__ P, const bf16* __restrict__ wt2,
    float* __restrict__ h2, float* __restrict__ stats)
{
    __shared__ __align__(16) short As[41472];      // 324 rows x 128 ci (82,944 B)
    __shared__ __align__(16) short Ws[2][16384];   // 2 x 128 o x 128 ci (65,536 B)
    __shared__ float sm[16];
    const int t = threadIdx.x;
    const int lane = t & 63, wid = t >> 6;
    const int lo = lane & 15, hi = lane >> 4;
    int b = ((blockIdx.x & 7) << 5) | (blockIdx.x >> 3);   // XCD-chunked, bijective (256=8x32)
    const int X = b >> 4, Y = b & 15;
    const int zg = wid >> 1, og = wid & 1;

    const char* Pb = (const char*)P;
    const char* Wb = (const char*)wt2;
    char* AsB = (char*)As;
    char* WsB = (char*)Ws;

    int wbyte[4], wswz[4];
    #pragma unroll
    for (int n = 0; n < 4; ++n) {
        int row = og * 64 + n * 16 + lo;
        wbyte[n] = row << 8;
        wswz[n] = (row & 7) << 4;
    }

    f32x4 acc[4][4];
    #pragma unroll
    for (int m = 0; m < 4; ++m)
        #pragma unroll
        for (int n = 0; n < 4; ++n) acc[m][n] = (f32x4){0.f, 0.f, 0.f, 0.f};

    for (int kxy = 0; kxy < 9; ++kxy) {
        int kx = kxy / 3, ky = kxy - kx * 3;
        __syncthreads();   // prev kxy readers of As/Ws done (full drain, 9x total)
        // stage As: 324 contiguous rows (x'=X+kx, y'=Y+ky, all z', all w')
        int rowstart = ((X + kx) * 18 + (Y + ky)) * 324;
        const char* gA = Pb + (size_t)rowstart * 256;
        for (int c = wid; c < 81; c += 8) {
            int L = c * 1024 + lane * 16;
            int srcoff = L ^ (((L >> 8) & 7) << 4);   // pre-swizzle source (rule #21)
            gload_lds16(gA + srcoff, AsB + c * 1024);
        }
        {   // stage first tap of sequence (s=0: kw=0,kz=0 -> tap kxy*9) into buf 0
            const char* gW = Wb + (size_t)(kxy * 9) * 32768;
            #pragma unroll
            for (int c = 0; c < 4; ++c) {
                int cc = wid + c * 8;
                int L = cc * 1024 + lane * 16;
                int srcoff = L ^ (((L >> 8) & 7) << 4);
                gload_lds16(gW + srcoff, WsB + cc * 1024);
            }
        }
        asm volatile("s_waitcnt vmcnt(0)" ::: "memory");
        __builtin_amdgcn_s_barrier();
        __builtin_amdgcn_sched_barrier(0);

        bf16x8 af[6][4];
        #pragma unroll
        for (int s = 0; s < 9; ++s) {
            const int kw = s / 3, kz = s - kw * 3;
            if (s > 0) {
                // barrier #1: all readers of buf[(s+1)&1] (step s-1 compute) are done
                __builtin_amdgcn_s_barrier();
                __builtin_amdgcn_sched_barrier(0);
            }
            if (s < 8) {
                // issue next tap's Ws loads into the other buffer
                const int s1 = s + 1;
                const int tap1 = (s1 - (s1 / 3) * 3) * 3 + (s1 / 3);   // kz1*3+kw1
                const char* gW = Wb + (size_t)(kxy * 9 + tap1) * 32768;
                char* dst = WsB + (s1 & 1) * 32768;
                #pragma unroll
                for (int c = 0; c < 4; ++c) {
                    int cc = wid + c * 8;
                    int L = cc * 1024 + lane * 16;
                    int srcoff = L ^ (((L >> 8) & 7) << 4);
                    gload_lds16(gW + srcoff, dst + cc * 1024);
                }
            }
            if (kz == 0) {
                // load 24 A-frags (rows zg*4+0..5, shifted by kw) serving kz=0..2
                #pragma unroll
                for (int r = 0; r < 6; ++r) {
                    int arow = (zg * 4 + r) * 18 + lo + kw;
                    int abase = arow << 8;
                    int aswz = (arow & 7) << 4;
                    #pragma unroll
                    for (int kk = 0; kk < 4; ++kk)
                        af[r][kk] = *(const bf16x8*)(AsB + abase + ((kk * 64 + hi * 16) ^ aswz));
                }
            }
            if (s < 8) { asm volatile("s_waitcnt vmcnt(4)" ::: "memory"); }
            else       { asm volatile("s_waitcnt vmcnt(0)" ::: "memory"); }
            __builtin_amdgcn_s_barrier();   // barrier #2: buf[s&1] fully staged for all
            __builtin_amdgcn_sched_barrier(0);
            const char* wb = WsB + (s & 1) * 32768;
            #pragma unroll
            for (int kk = 0; kk < 4; ++kk) {
                bf16x8 bb[4];
                #pragma unroll
                for (int n = 0; n < 4; ++n)
                    bb[n] = *(const bf16x8*)(wb + wbyte[n] + ((kk * 64 + hi * 16) ^ wswz[n]));
                #pragma unroll
                for (int m = 0; m < 4; ++m)
                    #pragma unroll
                    for (int n = 0; n < 4; ++n)
                        acc[m][n] = __builtin_amdgcn_mfma_f32_16x16x32_bf16(
                            af[m + kz][kk], bb[n], acc[m][n], 0, 0, 0);
            }
        }
    }

    // epilogue: D frag col(lane&15)=o, row((lane>>4)*4+e)=w -> float4 store along w
    float ls = 0.f, lq = 0.f;
    int sXY = (X * 16 + Y) * 16;
    #pragma unroll
    for (int m = 0; m < 4; ++m) {
        int z = zg * 4 + m;
        int s = (sXY + z) * 16 + hi * 4;
        #pragma unroll
        for (int n = 0; n < 4; ++n) {
            int o = og * 64 + n * 16 + lo;
            *(f32x4*)(h2 + (size_t)o * 65536 + s) = acc[m][n];
            #pragma unroll
            for (int e = 0; e < 4; ++e) { float v = acc[m][n][e]; ls += v; lq += v * v; }
        }
    }
    __syncthreads();
    block_reduce2(ls, lq, sm);
    if (t == 0) { atomicAdd(&stats[4], ls); atomicAdd(&stats[5], lq); }
}

// ---------------- K4: GN2 apply + GELU in place + per-channel sums for SE ----------------
__global__ __launch_bounds__(256) void k4_gn2_se(
    float* __restrict__ h2, const float* __restrict__ stats,
    const float* __restrict__ gw, const float* __restrict__ gb,
    float* __restrict__ chansum)
{
    __shared__ float sm[4];
    float mu = stats[4] * (1.f / 8388608.f);
    float var = stats[5] * (1.f / 8388608.f) - mu * mu;
    float rs = rsqrtf(var + EPSV);
    int chan = blockIdx.x >> 4, seg = blockIdx.x & 15;
    float w = gw[chan], bb = gb[chan];
    float lsum = 0.f;
    int base = chan * 65536 + seg * 4096;
    for (int k = 0; k < 16; ++k) {
        int i = base + k * 256 + threadIdx.x;
        float v = gelu_exact((h2[i] - mu) * rs * w + bb);
        h2[i] = v;
        lsum += v;
    }
    #pragma unroll
    for (int off = 32; off > 0; off >>= 1) lsum += __shfl_down(lsum, off);
    int lane = threadIdx.x & 63, wid = threadIdx.x >> 6;
    if (lane == 0) sm[wid] = lsum;
    __syncthreads();
    if (threadIdx.x == 0) atomicAdd(&chansum[chan], sm[0] + sm[1] + sm[2] + sm[3]);
}

// ---------------- K6: SE MLP inline + conv3 (128->32) + GN3 stats ----------------
__global__ __launch_bounds__(256) void k6_conv3(
    const float* __restrict__ h2, const float* __restrict__ w3,
    const float* __restrict__ chansum,
    const float* __restrict__ sw1, const float* __restrict__ sw2,
    float* __restrict__ h3, float* __restrict__ stats)
{
    __shared__ float We[128 * 32];   // [ci][oc]
    __shared__ float sesc[128];
    __shared__ float t1s[8];
    __shared__ float sm[16];
    int t = threadIdx.x;
    // inline SE MLP (redundant per block, ~2K MAC)
    if (t < 8) {
        float a = 0.f;
        for (int o = 0; o < 128; ++o) a += sw1[t * 128 + o] * chansum[o];
        t1s[t] = gelu_exact(a * (1.f / 65536.f));
    }
    __syncthreads();
    if (t < 128) {
        float a = 0.f;
        #pragma unroll
        for (int d = 0; d < 8; ++d) a += sw2[t * 8 + d] * t1s[d];
        sesc[t] = 1.f / (1.f + expf(-a));
    }
    __syncthreads();
    for (int i = t; i < 4096; i += 256) {
        int ci = i >> 5, oc = i & 31;
        We[i] = w3[oc * 128 + ci] * sesc[ci];
    }
    __syncthreads();
    int s = blockIdx.x * 256 + t;
    float acc[32];
    #pragma unroll
    for (int j = 0; j < 32; ++j) acc[j] = 0.f;
    for (int ci = 0; ci < 128; ++ci) {
        float hv = h2[ci * 65536 + s];
        const float4* wr = (const float4*)&We[ci * 32];
        #pragma unroll
        for (int j4 = 0; j4 < 8; ++j4) {
            float4 wv = wr[j4];
            acc[j4*4+0] += hv * wv.x; acc[j4*4+1] += hv * wv.y;
            acc[j4*4+2] += hv * wv.z; acc[j4*4+3] += hv * wv.w;
        }
    }
    float ls = 0.f, lq = 0.f;
    #pragma unroll
    for (int j = 0; j < 32; ++j) {
        float v = acc[j];
        h3[j * 65536 + s] = v;
        ls += v; lq += v * v;
    }
    block_reduce2(ls, lq, sm);
    if (t == 0) { atomicAdd(&stats[6], ls); atomicAdd(&stats[7], lq); }
}

// ---------------- K7: GN3 apply -> out ----------------
__global__ __launch_bounds__(256) void k7_gn3(
    const float* __restrict__ h3, const float* __restrict__ stats,
    const float* __restrict__ gw, const float* __restrict__ gb,
    float* __restrict__ out)
{
    float mu = stats[6] * (1.f / 2097152.f);
    float var = stats[7] * (1.f / 2097152.f) - mu * mu;
    float rs = rsqrtf(var + EPSV);
    int idx = blockIdx.x * 256 + threadIdx.x;
    int c = idx >> 16;
    out[idx] = (h3[idx] - mu) * rs * gw[c] + gb[c];
}

// ---------------- launch ----------------
extern "C" void kernel_launch(void* const* d_in, const int* in_sizes, int n_in,
                              void* d_out, int out_size, void* d_ws, size_t ws_size,
                              hipStream_t stream)
{
    const float* x    = (const float*)d_in[0];
    const float* g0w  = (const float*)d_in[1];
    const float* g0b  = (const float*)d_in[2];
    const float* w1   = (const float*)d_in[3];
    const float* gn1w = (const float*)d_in[4];
    const float* gn1b = (const float*)d_in[5];
    const float* w2   = (const float*)d_in[6];
    const float* gn2w = (const float*)d_in[7];
    const float* gn2b = (const float*)d_in[8];
    const float* sw1  = (const float*)d_in[9];
    const float* sw2  = (const float*)d_in[10];
    const float* w3   = (const float*)d_in[11];
    const float* gn3w = (const float*)d_in[12];
    const float* gn3b = (const float*)d_in[13];
    float* out = (float*)d_out;

    char* ws = (char*)d_ws;
    float* stats   = (float*)ws;            // [0..7] sums, [64..191] chansum
    float* chansum = stats + 64;
    bf16*  wt2  = (bf16*)(ws + 4096);                 // 81*128*128 bf16 = 2,654,208 B
    bf16*  P    = (bf16*)(ws + 2658304);              // 18^4 x 128 bf16 = 26,873,856 B
    float* hbuf = (float*)(ws + 29532160);            // h1 then h2, 33,554,432 B
    float* h3   = (float*)(ws + 63086592);            // 8,388,608 B

    hipMemsetAsync(stats, 0, 4096, stream);
    hipMemsetAsync(P, 0, (size_t)104976 * 128 * 2, stream);
    kw_k0<<<6208, 256, 0, stream>>>(w2, wt2, x, stats);
    k1_conv1<<<256, 256, 0, stream>>>(x, w1, g0w, g0b, hbuf, stats);
    k2_gn1_pad<<<1024, 256, 0, stream>>>(hbuf, P, stats, gn1w, gn1b);
    k3_conv2<<<256, 512, 0, stream>>>(P, wt2, hbuf, stats);
    k4_gn2_se<<<2048, 256, 0, stream>>>(hbuf, stats, gn2w, gn2b, chansum);
    k6_conv3<<<256, 256, 0, stream>>>(hbuf, w3, chansum, sw1, sw2, h3, stats);
    k7_gn3<<<8192, 256, 0, stream>>>(h3, stats, gn3w, gn3b, out);
}